// Round 4
// baseline (153.857 us; speedup 1.0000x reference)
//
#include <hip/hip_runtime.h>

#define B_N 256
#define IC_N 1152
#define J_N 10
#define D_N 16

typedef __attribute__((ext_vector_type(8))) short short8;
typedef __attribute__((ext_vector_type(4))) float floatx4;

union u4s8 { uint4 u; short8 s; };

__device__ __forceinline__ float bf_lo(unsigned int u){
  union { unsigned int i; float f; } c; c.i = u << 16; return c.f;
}
__device__ __forceinline__ float bf_hi(unsigned int u){
  union { unsigned int i; float f; } c; c.i = u & 0xffff0000u; return c.f;
}
__device__ __forceinline__ unsigned int rne16(float f){
  union { float ff; unsigned int i; } c; c.ff = f;
  return (c.i + 0x7FFFu + ((c.i >> 16) & 1u)) >> 16;
}
__device__ __forceinline__ unsigned int pack_rne(float lo, float hi){
  return rne16(lo) | (rne16(hi) << 16);
}
__device__ __forceinline__ unsigned int pack_trunc(float lo, float hi){
  union { float f; unsigned int u; } a, b; a.f = lo; b.f = hi;
  return __builtin_amdgcn_perm(b.u, a.u, 0x07060302u);
}

// prep: identical layout emits (verified R5..R13). vsum zeroing dropped —
// vsum is now written (not accumulated) by pass round 1's by==0 blocks.
__global__ __launch_bounds__(256) void caps_prep(
    const float* __restrict__ W, uint4* __restrict__ wsf,
    uint4* __restrict__ wcc2)
{
  const int tid = threadIdx.x;
  __shared__ unsigned int lw[1024];
  const int j = blockIdx.x / 72, itile = blockIdx.x % 72;
  const float4* Wt = (const float4*)(W + ((size_t)(j * IC_N + itile * 16) << 7));
  #pragma unroll
  for (int h = 0; h < 2; ++h) {
    const float4 f = Wt[h * 256 + tid];
    lw[(h * 256 + tid) * 2]     = pack_rne(f.x, f.y);
    lw[(h * 256 + tid) * 2 + 1] = pack_rne(f.z, f.w);
  }
  __syncthreads();
  {  // wsf emit
    const int ktl = tid >> 6, ln = tid & 63;
    const int base = (ktl * 4 + (ln >> 4)) * 64 + (ln & 15) * 4;
    uint4 q;
    q.x = lw[base]; q.y = lw[base + 1]; q.z = lw[base + 2]; q.w = lw[base + 3];
    wsf[((size_t)j * 288 + itile * 4 + ktl) * 64 + ln] = q;
  }
  {  // wcc2 emit
    const int e = tid >> 5, lane2 = tid & 31;
    const int il = lane2 & 15, dbase = (lane2 >> 4) * 8;
    unsigned short h[8];
    #pragma unroll
    for (int k = 0; k < 8; ++k) {
      const unsigned int u = lw[il * 64 + (dbase + k) * 4 + (e >> 1)];
      h[k] = (e & 1) ? (unsigned short)(u >> 16) : (unsigned short)(u & 0xffffu);
    }
    uint4 q;
    q.x = h[0] | ((unsigned int)h[1] << 16);
    q.y = h[2] | ((unsigned int)h[3] << 16);
    q.z = h[4] | ((unsigned int)h[5] << 16);
    q.w = h[6] | ((unsigned int)h[7] << 16);
    wcc2[(((size_t)j * 8 + e) * 72 + itile) * 32 + lane2] = q;
  }
}

// Pass (R3 backbone: 16x36, 640 thr, 32-i chunks) + SQUASH PROLOGUE:
// for round>0 each block redundantly recomputes squash(prev round) for its
// own btile from sp_prev (double-buffered vs sp_cur, so no intra-dispatch
// race; ordering = plain kernel boundaries, NO fences/atomics — R1/R2
// lesson). av fragment is built in-registers via per-wave LDS transpose;
// all math/rounding bit-identical to the old separate squash kernel.
__global__ __launch_bounds__(640, 5) void caps_pass(
    const float* __restrict__ x,
    const uint4* __restrict__ wsf, const uint4* __restrict__ wcc2,
    const float* __restrict__ sp_prev, float* __restrict__ sp_cur,
    float* __restrict__ vsum, const int round)
{
  __shared__ float ccl[10 * 32 * 17];      // 21.8 KB
  __shared__ unsigned int xt[32 * 17 * 4]; // [i 0..31][b pad17] uint4, 8.7 KB
  __shared__ float vs_l[10][16 * 17];      // per-wave vt[b][d] scratch, 10.9 KB

  const int tid  = threadIdx.x;
  const int wave = tid >> 6;              // = j
  const int lane = tid & 63;
  const int quad = lane >> 4;
  const int col  = lane & 15;
  const int b0   = blockIdx.x << 4;
  const int i0   = blockIdx.y << 5;       // 32 i per block

  // ---- stage x tile: 512 threads x 2 iters, 512-B coalesced runs ----
  if (tid < 512) {
    const int b = tid >> 5, j4 = tid & 31;
    const int half = j4 & 1;
    #pragma unroll
    for (int ii = 0; ii < 2; ++ii) {
      const int i = ii * 16 + (j4 >> 1);
      const float4 v = ((const float4*)(x + ((size_t)((b0 + b) * IC_N + i0 + i) << 3)))[half];
      const int idx = ((i * 17 + b) << 2) + (half << 1);
      xt[idx]     = pack_rne(v.x, v.y);
      xt[idx + 1] = pack_rne(v.z, v.w);
    }
  }

  short8 av = {0,0,0,0,0,0,0,0};
  if (round > 0) {
    // ---- squash(prev) prologue: wave j -> vt for all 16 b of this btile ----
    const float* slab = sp_prev + ((size_t)(blockIdx.x * 10 + wave) * 16) * 576;
    #pragma unroll 2
    for (int b = 0; b < 16; ++b) {
      const float* pb = slab + b * 576;
      float a = 0.f;
      #pragma unroll
      for (int q = 0; q < 9; ++q) a += pb[q * 64 + lane];
      a += __shfl_xor(a, 16, 64);
      a += __shfl_xor(a, 32, 64);
      const float s = a;
      float sq = s * s;
      sq += __shfl_xor(sq, 1, 16);
      sq += __shfl_xor(sq, 2, 16);
      sq += __shfl_xor(sq, 4, 16);
      sq += __shfl_xor(sq, 8, 16);
      const float coef = (sq / (1.f + sq)) * rsqrtf(sq + 1e-7f);
      const float v = coef * s;
      const int bj = (b0 + b) * J_N + wave;
      float vt = v;
      if (round == 2) vt += vsum[bj * 16 + col];  // accumulated v-sum (R7 lesson)
      if (lane < 16) {
        vs_l[wave][b * 17 + lane] = vt;
        if (round == 1 && blockIdx.y == 0) vsum[bj * 16 + lane] = vt;
      }
    }
    // av[lane] = bf16(vt[b=col][d=quad*8+0..7]) — same-wave LDS RAW only
    if (quad < 2) {
      unsigned int* aq = (unsigned int*)&av;
      #pragma unroll
      for (int m = 0; m < 4; ++m) {
        const float lo = vs_l[wave][col * 17 + quad * 8 + 2 * m];
        const float hi = vs_l[wave][col * 17 + quad * 8 + 2 * m + 1];
        aq[m] = pack_rne(lo, hi);
      }
    }
  }
  __syncthreads();
  const uint4* xtq = (const uint4*)xt;

  if (round > 0) {
    #pragma unroll
    for (int c = 0; c < 2; ++c) {         // two 16-i chunks, sequential
      uint4 bvq[8];
      #pragma unroll
      for (int e = 0; e < 8; ++e) {
        uint4 q = {0u, 0u, 0u, 0u};
        if (lane < 32)
          q = wcc2[(((size_t)wave * 8 + e) * 72 + (blockIdx.y * 2 + c)) * 32 + lane];
        bvq[e] = q;
      }
      uint4 xr[4];                        // x[b=quad*4+r][i=c*16+col]
      #pragma unroll
      for (int r = 0; r < 4; ++r)
        xr[r] = xtq[(c * 16 + col) * 17 + quad * 4 + r];
      floatx4 cc4 = {0.f, 0.f, 0.f, 0.f};
      #pragma unroll
      for (int e = 0; e < 8; ++e) {
        u4s8 bv; bv.u = bvq[e];
        floatx4 tf = {0.f, 0.f, 0.f, 0.f};
        tf = __builtin_amdgcn_mfma_f32_16x16x32_bf16(av, bv.s, tf, 0, 0, 0);
        #pragma unroll
        for (int r = 0; r < 4; ++r) {
          const unsigned int u = ((const unsigned int*)&xr[r])[e >> 1];
          const float xe = (e & 1) ? bf_hi(u) : bf_lo(u);
          cc4[r] += tf[r] * xe;
        }
      }
      #pragma unroll
      for (int r = 0; r < 4; ++r)
        ccl[(wave * 32 + c * 16 + col) * 17 + quad * 4 + r] = cc4[r];
    }
    __syncthreads();
    if (tid < 512) {                      // softmax over j per (i,b), in place
      const int i = tid >> 4, b = tid & 15;
      float cc[10];
      #pragma unroll
      for (int j = 0; j < 10; ++j) cc[j] = ccl[(j * 32 + i) * 17 + b];
      float m = cc[0];
      #pragma unroll
      for (int j = 1; j < 10; ++j) m = fmaxf(m, cc[j]);
      float den = 0.f;
      #pragma unroll
      for (int j = 0; j < 10; ++j) { cc[j] = __expf(cc[j] - m); den += cc[j]; }
      const float rd = __builtin_amdgcn_rcpf(den);
      #pragma unroll
      for (int j = 0; j < 10; ++j) ccl[(j * 32 + i) * 17 + b] = cc[j] * rd;
    }
    __syncthreads();
  }

  // Phase B: s[b,d] += (c*x) @ Ws, K=256 (8 kt); x from LDS, W from global
  floatx4 acc = {0.f, 0.f, 0.f, 0.f};
  #pragma unroll
  for (int kt = 0; kt < 8; ++kt) {
    const int il = kt * 4 + quad;         // i 0..31
    const uint4 xq = xtq[il * 17 + col];  // x[i=il][b=col]
    const uint4 wf = wsf[((size_t)wave * 288 + (blockIdx.y << 3) + kt) * 64 + lane];
    const float c = (round > 0) ? ccl[(wave * 32 + il) * 17 + col] : 0.1f;
    short8 af;
    unsigned int* aq = (unsigned int*)&af;
    aq[0] = pack_trunc(bf_lo(xq.x) * c, bf_hi(xq.x) * c);
    aq[1] = pack_trunc(bf_lo(xq.y) * c, bf_hi(xq.y) * c);
    aq[2] = pack_trunc(bf_lo(xq.z) * c, bf_hi(xq.z) * c);
    aq[3] = pack_trunc(bf_lo(xq.w) * c, bf_hi(xq.w) * c);
    u4s8 bw; bw.u = wf;
    acc = __builtin_amdgcn_mfma_f32_16x16x32_bf16(af, bw.s, acc, 0, 0, 0);
  }
  // sp_cur[btile][j][b=quad*4+r][ch36][d=col]
  float* sp = sp_cur + ((((size_t)blockIdx.x * 10 + wave) * 16 + quad * 4) * 36
                        + blockIdx.y) * 16 + col;
  #pragma unroll
  for (int r = 0; r < 4; ++r) sp[(size_t)r * 36 * 16] = acc[r];
}

// final squash only (round 2 -> out). One wave per (b,j); 9 coalesced loads.
__global__ __launch_bounds__(256) void caps_squash_final(
    const float* __restrict__ s_part, float* __restrict__ out)
{
  const int tid  = threadIdx.x;
  const int w    = tid >> 6;
  const int lane = tid & 63;
  const int bj   = blockIdx.x * 4 + w;
  const int b    = bj / 10, j = bj - b * 10;
  const int btile = b >> 4, brem = b & 15;
  const float* base = s_part + (((size_t)btile * 10 + j) * 16 + brem) * 576;
  float acc = 0.f;
  #pragma unroll
  for (int q = 0; q < 9; ++q) acc += base[q * 64 + lane];
  acc += __shfl_xor(acc, 16, 64);
  acc += __shfl_xor(acc, 32, 64);
  const float s = acc;
  float sq = s * s;
  sq += __shfl_xor(sq, 1, 16);
  sq += __shfl_xor(sq, 2, 16);
  sq += __shfl_xor(sq, 4, 16);
  sq += __shfl_xor(sq, 8, 16);
  const float coef = (sq / (1.f + sq)) * rsqrtf(sq + 1e-7f);
  const float v = coef * s;
  if (lane < 16) out[bj * 16 + lane] = v;
}

extern "C" void kernel_launch(void* const* d_in, const int* in_sizes, int n_in,
                              void* d_out, int out_size, void* d_ws, size_t ws_size,
                              hipStream_t stream)
{
  const float* x_p = (const float*)d_in[0];   // [256][1152][8] fp32
  const float* W_p = (const float*)d_in[1];   // [10][1152][16][8] fp32

  // ws: wsf 2.95M | wcc2 2.95M | s_part A+B (2 x 5.9M) | vsum 164K
  uint4* wsf   = (uint4*)d_ws;
  uint4* wcc2  = wsf + 184320;
  float* spA   = (float*)(wcc2 + 184320);             // 1474560 f
  float* spB   = spA + 1474560;                       // 1474560 f
  float* vsum  = spB + 1474560;                       // 40960 f
  float* out_p = (float*)d_out;

  caps_prep<<<dim3(720), dim3(256), 0, stream>>>(W_p, wsf, wcc2);
  // r0: -> spA ; r1: squash(spA) -> spB ; r2: squash(spB)+vsum -> spA
  caps_pass<<<dim3(16, 36), dim3(640), 0, stream>>>(
      x_p, wsf, wcc2, spA, spA, vsum, 0);
  caps_pass<<<dim3(16, 36), dim3(640), 0, stream>>>(
      x_p, wsf, wcc2, spA, spB, vsum, 1);
  caps_pass<<<dim3(16, 36), dim3(640), 0, stream>>>(
      x_p, wsf, wcc2, spB, spA, vsum, 2);
  caps_squash_final<<<dim3(640), dim3(256), 0, stream>>>(spA, out_p);
}

// Round 5
// 110.240 us; speedup vs baseline: 1.3957x; 1.3957x over previous
//
#include <hip/hip_runtime.h>

#define B_N 256
#define IC_N 1152
#define J_N 10
#define D_N 16

typedef __attribute__((ext_vector_type(8))) short short8;
typedef __attribute__((ext_vector_type(4))) float floatx4;

union u4s8 { uint4 u; short8 s; };

__device__ __forceinline__ float bf_lo(unsigned int u){
  union { unsigned int i; float f; } c; c.i = u << 16; return c.f;
}
__device__ __forceinline__ float bf_hi(unsigned int u){
  union { unsigned int i; float f; } c; c.i = u & 0xffff0000u; return c.f;
}
__device__ __forceinline__ unsigned int rne16(float f){
  union { float ff; unsigned int i; } c; c.ff = f;
  return (c.i + 0x7FFFu + ((c.i >> 16) & 1u)) >> 16;
}
__device__ __forceinline__ unsigned int pack_rne(float lo, float hi){
  return rne16(lo) | (rne16(hi) << 16);
}
__device__ __forceinline__ unsigned int pack_trunc(float lo, float hi){
  union { float f; unsigned int u; } a, b; a.f = lo; b.f = hi;
  return __builtin_amdgcn_perm(b.u, a.u, 0x07060302u);
}

// prep: identical to the verified R0/R3 kernel (layouts R5..R13).
__global__ __launch_bounds__(256) void caps_prep(
    const float* __restrict__ W, uint4* __restrict__ wsf,
    uint4* __restrict__ wcc2, float* __restrict__ vsum)
{
  const int tid = threadIdx.x;
  const int t0 = blockIdx.x * 256 + tid;
  if (t0 < B_N * J_N * D_N) vsum[t0] = 0.f;
  __shared__ unsigned int lw[1024];
  const int j = blockIdx.x / 72, itile = blockIdx.x % 72;
  const float4* Wt = (const float4*)(W + ((size_t)(j * IC_N + itile * 16) << 7));
  #pragma unroll
  for (int h = 0; h < 2; ++h) {
    const float4 f = Wt[h * 256 + tid];
    lw[(h * 256 + tid) * 2]     = pack_rne(f.x, f.y);
    lw[(h * 256 + tid) * 2 + 1] = pack_rne(f.z, f.w);
  }
  __syncthreads();
  {  // wsf emit
    const int ktl = tid >> 6, ln = tid & 63;
    const int base = (ktl * 4 + (ln >> 4)) * 64 + (ln & 15) * 4;
    uint4 q;
    q.x = lw[base]; q.y = lw[base + 1]; q.z = lw[base + 2]; q.w = lw[base + 3];
    wsf[((size_t)j * 288 + itile * 4 + ktl) * 64 + ln] = q;
  }
  {  // wcc2 emit
    const int e = tid >> 5, lane2 = tid & 31;
    const int il = lane2 & 15, dbase = (lane2 >> 4) * 8;
    unsigned short h[8];
    #pragma unroll
    for (int k = 0; k < 8; ++k) {
      const unsigned int u = lw[il * 64 + (dbase + k) * 4 + (e >> 1)];
      h[k] = (e & 1) ? (unsigned short)(u >> 16) : (unsigned short)(u & 0xffffu);
    }
    uint4 q;
    q.x = h[0] | ((unsigned int)h[1] << 16);
    q.y = h[2] | ((unsigned int)h[3] << 16);
    q.z = h[4] | ((unsigned int)h[5] << 16);
    q.w = h[6] | ((unsigned int)h[7] << 16);
    wcc2[(((size_t)j * 8 + e) * 72 + itile) * 32 + lane2] = q;
  }
}

// Pass: R3 backbone (32-i chunks, 576 blocks) with three latency fixes:
//  (1) XCD-aware bijective swizzle (m204): the 16 btile-blocks of one
//      by-slice land on ONE XCD -> wsf/wcc2/x slices L2-resident (per-XCD
//      working set ~420KB << 4MB).
//  (2) wf8 register prefetch: all 8 wsf loads issued before the softmax
//      barriers (round>0) / at top (round 0) -> ~600cy latency hidden.
//  (3) phase-B accumulator split into 2 independent 4-MFMA chains.
// All index math / layouts / rounding identical to R3.
__global__ __launch_bounds__(640, 5) void caps_pass(
    const float* __restrict__ x,
    const uint4* __restrict__ wsf, const uint4* __restrict__ wcc2,
    const uint4* __restrict__ vsbf, float* __restrict__ s_part, const int round)
{
  __shared__ float ccl[10 * 32 * 17];     // 21.8 KB
  __shared__ unsigned int xt[32 * 17 * 4];// [i 0..31][b pad17] uint4, 8.7 KB

  const int tid  = threadIdx.x;
  const int wave = tid >> 6;              // = j
  const int lane = tid & 63;
  const int quad = lane >> 4;
  const int col  = lane & 15;

  // XCD swizzle: 576 blocks = 8 xcd * 72; contiguous work per XCD.
  const int bid = blockIdx.x;
  const int wid = (bid & 7) * 72 + (bid >> 3);
  const int bx  = wid & 15;               // btile
  const int by  = wid >> 4;               // i-chunk 0..35
  const int b0  = bx << 4;
  const int i0  = by << 5;                // 32 i per block

  // ---- stage x tile: 512 threads x 2 iters, 512-B coalesced runs ----
  if (tid < 512) {
    const int b = tid >> 5, j4 = tid & 31;
    const int half = j4 & 1;
    #pragma unroll
    for (int ii = 0; ii < 2; ++ii) {
      const int i = ii * 16 + (j4 >> 1);
      const float4 v = ((const float4*)(x + ((size_t)((b0 + b) * IC_N + i0 + i) << 3)))[half];
      const int idx = ((i * 17 + b) << 2) + (half << 1);
      xt[idx]     = pack_rne(v.x, v.y);
      xt[idx + 1] = pack_rne(v.z, v.w);
    }
  }

  uint4 wf8[8];                           // phase-B W fragments, prefetched
  if (round == 0) {
    #pragma unroll
    for (int kt = 0; kt < 8; ++kt)
      wf8[kt] = wsf[((size_t)wave * 288 + (by << 3) + kt) * 64 + lane];
  }
  __syncthreads();
  const uint4* xtq = (const uint4*)xt;

  if (round > 0) {
    short8 av = {0,0,0,0,0,0,0,0};        // vsum[b=col][d=quad*8+..]; q2,3 pad
    if (quad < 2)
      av = *(const short8*)&vsbf[((size_t)(b0 + col) * J_N + wave) * 2 + quad];
    #pragma unroll
    for (int c = 0; c < 2; ++c) {         // two 16-i chunks, sequential
      uint4 bvq[8];
      #pragma unroll
      for (int e = 0; e < 8; ++e) {
        uint4 q = {0u, 0u, 0u, 0u};
        if (lane < 32)
          q = wcc2[(((size_t)wave * 8 + e) * 72 + (by * 2 + c)) * 32 + lane];
        bvq[e] = q;
      }
      uint4 xr[4];                        // x[b=quad*4+r][i=c*16+col]
      #pragma unroll
      for (int r = 0; r < 4; ++r)
        xr[r] = xtq[(c * 16 + col) * 17 + quad * 4 + r];
      floatx4 cc4 = {0.f, 0.f, 0.f, 0.f};
      #pragma unroll
      for (int e = 0; e < 8; ++e) {
        u4s8 bv; bv.u = bvq[e];
        floatx4 tf = {0.f, 0.f, 0.f, 0.f};
        tf = __builtin_amdgcn_mfma_f32_16x16x32_bf16(av, bv.s, tf, 0, 0, 0);
        #pragma unroll
        for (int r = 0; r < 4; ++r) {
          const unsigned int u = ((const unsigned int*)&xr[r])[e >> 1];
          const float xe = (e & 1) ? bf_hi(u) : bf_lo(u);
          cc4[r] += tf[r] * xe;
        }
      }
      #pragma unroll
      for (int r = 0; r < 4; ++r)
        ccl[(wave * 32 + c * 16 + col) * 17 + quad * 4 + r] = cc4[r];
    }
    // prefetch wsf NOW: latency hides under ccl write + softmax + barriers
    #pragma unroll
    for (int kt = 0; kt < 8; ++kt)
      wf8[kt] = wsf[((size_t)wave * 288 + (by << 3) + kt) * 64 + lane];
    __syncthreads();
    if (tid < 512) {                      // softmax over j per (i,b), in place
      const int i = tid >> 4, b = tid & 15;
      float cc[10];
      #pragma unroll
      for (int j = 0; j < 10; ++j) cc[j] = ccl[(j * 32 + i) * 17 + b];
      float m = cc[0];
      #pragma unroll
      for (int j = 1; j < 10; ++j) m = fmaxf(m, cc[j]);
      float den = 0.f;
      #pragma unroll
      for (int j = 0; j < 10; ++j) { cc[j] = __expf(cc[j] - m); den += cc[j]; }
      const float rd = __builtin_amdgcn_rcpf(den);
      #pragma unroll
      for (int j = 0; j < 10; ++j) ccl[(j * 32 + i) * 17 + b] = cc[j] * rd;
    }
    __syncthreads();
  }

  // Phase B: s[b,d] += (c*x) @ Ws, K=256; two independent 4-MFMA chains.
  floatx4 acc0 = {0.f, 0.f, 0.f, 0.f};
  floatx4 acc1 = {0.f, 0.f, 0.f, 0.f};
  #pragma unroll
  for (int kt = 0; kt < 8; ++kt) {
    const int il = kt * 4 + quad;         // i 0..31
    const uint4 xq = xtq[il * 17 + col];  // x[i=il][b=col]
    const float c = (round > 0) ? ccl[(wave * 32 + il) * 17 + col] : 0.1f;
    short8 af;
    unsigned int* aq = (unsigned int*)&af;
    aq[0] = pack_trunc(bf_lo(xq.x) * c, bf_hi(xq.x) * c);
    aq[1] = pack_trunc(bf_lo(xq.y) * c, bf_hi(xq.y) * c);
    aq[2] = pack_trunc(bf_lo(xq.z) * c, bf_hi(xq.z) * c);
    aq[3] = pack_trunc(bf_lo(xq.w) * c, bf_hi(xq.w) * c);
    u4s8 bw; bw.u = wf8[kt];
    if (kt & 1)
      acc1 = __builtin_amdgcn_mfma_f32_16x16x32_bf16(af, bw.s, acc1, 0, 0, 0);
    else
      acc0 = __builtin_amdgcn_mfma_f32_16x16x32_bf16(af, bw.s, acc0, 0, 0, 0);
  }
  const floatx4 acc = acc0 + acc1;
  // s_part[btile][j][b=quad*4+r][ch36][d=col]
  float* sp = s_part + ((((size_t)bx * 10 + wave) * 16 + quad * 4) * 36
                        + by) * 16 + col;
  #pragma unroll
  for (int r = 0; r < 4; ++r) sp[(size_t)r * 36 * 16] = acc[r];
}

// squash: one wave per (b,j); 9 coalesced loads (36 chunks). Unchanged R3.
__global__ __launch_bounds__(256) void caps_squash(
    const float* __restrict__ s_part, float* __restrict__ vsum,
    unsigned int* __restrict__ vsbf_u, float* __restrict__ out, const int round)
{
  const int tid  = threadIdx.x;
  const int w    = tid >> 6;
  const int lane = tid & 63;
  const int bj   = blockIdx.x * 4 + w;
  const int b    = bj / 10, j = bj - b * 10;
  const int btile = b >> 4, brem = b & 15;
  const float* base = s_part + (((size_t)btile * 10 + j) * 16 + brem) * 576;
  float acc = 0.f;
  #pragma unroll
  for (int q = 0; q < 9; ++q) acc += base[q * 64 + lane];
  acc += __shfl_xor(acc, 16, 64);
  acc += __shfl_xor(acc, 32, 64);
  const float s = acc;
  float sq = s * s;
  sq += __shfl_xor(sq, 1, 16);
  sq += __shfl_xor(sq, 2, 16);
  sq += __shfl_xor(sq, 4, 16);
  sq += __shfl_xor(sq, 8, 16);
  const float coef = (sq / (1.f + sq)) * rsqrtf(sq + 1e-7f);
  const float v = coef * s;
  if (round < 2) {
    const float vprev = (lane < 16) ? vsum[bj * 16 + lane] : 0.f;
    const float vt = vprev + v;
    const float vtn = __shfl_down(vt, 1, 64);
    if (lane < 16) {
      vsum[bj * 16 + lane] = vt;
      if (!(lane & 1))
        vsbf_u[bj * 8 + (lane >> 1)] = pack_rne(vt, vtn);
    }
  } else if (lane < 16) {
    out[bj * 16 + lane] = v;
  }
}

extern "C" void kernel_launch(void* const* d_in, const int* in_sizes, int n_in,
                              void* d_out, int out_size, void* d_ws, size_t ws_size,
                              hipStream_t stream)
{
  const float* x_p = (const float*)d_in[0];   // [256][1152][8] fp32
  const float* W_p = (const float*)d_in[1];   // [10][1152][16][8] fp32

  uint4* wsf   = (uint4*)d_ws;
  uint4* wcc2  = wsf + 184320;
  float* s_prt = (float*)(wcc2 + 184320);             // region 2949120 f
  float* vsum  = s_prt + 2949120;                     // 40960 f
  unsigned int* vsbf_u = (unsigned int*)(vsum + 40960);
  float* out_p = (float*)d_out;

  caps_prep<<<dim3(720), dim3(256), 0, stream>>>(W_p, wsf, wcc2, vsum);
  for (int r = 0; r < 3; ++r) {
    caps_pass<<<dim3(576), dim3(640), 0, stream>>>(
        x_p, wsf, wcc2, (const uint4*)vsbf_u, s_prt, r);
    caps_squash<<<dim3(640), dim3(256), 0, stream>>>(
        s_prt, vsum, vsbf_u, out_p, r);
  }
}